// Round 8
// baseline (270.226 us; speedup 1.0000x reference)
//
#include <hip/hip_runtime.h>

typedef __bf16 bf16x8 __attribute__((ext_vector_type(8)));
typedef __bf16 bf16x2 __attribute__((ext_vector_type(2)));
typedef float  f32x4  __attribute__((ext_vector_type(4)));
typedef float  f32x2  __attribute__((ext_vector_type(2)));
typedef unsigned long long u64;

#define MFMA(a, b, c) __builtin_amdgcn_mfma_f32_16x16x32_bf16((a), (b), (c), 0, 0, 0)

// Packed fp32 helpers -> v_pk_fma_f32 / v_pk_max_f32 (bit-exact per element).
__device__ __forceinline__ f32x2 fma2(f32x2 a, f32x2 b, f32x2 c) {
    return __builtin_elementwise_fma(a, b, c);
}
__device__ __forceinline__ f32x2 relu2(f32x2 a) {
    f32x2 z = {0.0f, 0.0f};
    return __builtin_elementwise_max(a, z);
}
// Double-bf16 (hi/lo) split of a packed f32 pair; word layout = MFMA frag word.
__device__ __forceinline__ void hilo2(f32x2 h, unsigned& hiw, unsigned& low) {
    bf16x2 hb = __builtin_convertvector(h, bf16x2);
    unsigned hw = __builtin_bit_cast(unsigned, hb);
    f32x2 hf;
    hf[0] = __builtin_bit_cast(float, hw << 16);
    hf[1] = __builtin_bit_cast(float, hw & 0xFFFF0000u);
    f32x2 lo = h - hf;
    bf16x2 lb = __builtin_convertvector(lo, bf16x2);
    hiw = hw;
    low = __builtin_bit_cast(unsigned, lb);
}
__device__ __forceinline__ bf16x8 frag4(unsigned w0, unsigned w1, unsigned w2, unsigned w3) {
    uint4 u; u.x = w0; u.y = w1; u.z = w2; u.w = w3;
    return __builtin_bit_cast(bf16x8, u);
}

// __launch_bounds__(256, 4): combined VGPR+AGPR budget 128 -> 4 waves/SIMD.
// Round-1's failure was forcing this budget at ~170 regs of demand (40+ spilled).
// This version first CUTS demand: weights (48 persistent regs) -> per-iter LDS
// broadcast reads; self-neighbor pinned to row 0 frees relbuf rows for the
// weight stage. Estimated peak ~100-110 combined -> fits without spill.
__global__ __launch_bounds__(256, 4) void miniemb_kernel(
    const float* __restrict__ windows,
    const float* __restrict__ W1, const float* __restrict__ b1,
    const float* __restrict__ W2, const float* __restrict__ b2,
    const float* __restrict__ W3, const float* __restrict__ b3,
    float* __restrict__ out)
{
    // LDS total = 23040 + 768 + 16384 = 40192 B -> 4 blocks/CU.
    __shared__ float relbuf[45 * 128];   // rows 1..15 only (row 0 = self = zeros)
    __shared__ float wlds[192];          // [0,96)=W1, [96,128)=b1, [128,192)=b2
    __shared__ uint4 w3lds[16][64];      // W3 B-frags; first 2 KiB doubles as pts4

    float (*pts4)[4] = reinterpret_cast<float(*)[4]>(&w3lds[0][0]);

    const int m    = blockIdx.x;
    const int tid  = threadIdx.x;
    const int w    = tid >> 6;
    const int lane = tid & 63;
    const int g    = lane >> 4;
    const int ln   = lane & 15;

    // ---- phase 0: stage pts4 (x,y,z,|p|^2) + small weights into LDS ----
    const float* wm = windows + (size_t)m * 128 * 3;
    if (tid < 128) {
        float x = wm[tid * 3], y = wm[tid * 3 + 1], z = wm[tid * 3 + 2];
        float s = __fadd_rn(__fadd_rn(__fmul_rn(x, x), __fmul_rn(y, y)),
                            __fmul_rn(z, z));
        f32x4 P = {x, y, z, s};
        *(f32x4*)&pts4[tid][0] = P;
    }
    if (tid < 192)
        wlds[tid] = (tid < 96) ? W1[tid] : (tid < 128 ? b1[tid - 96] : b2[tid - 128]);
    __syncthreads();

    // ---- phase 1: kNN scan, 2 threads per point, sorted insert (breadth-wise) ----
    const int k = tid >> 1;      // point
    const int h = tid & 1;       // half
    f32x4 Q = *(const f32x4*)&pts4[k][0];
    u64 bd[16];
    #pragma unroll
    for (int t = 0; t < 16; ++t) bd[t] = ~0ull;
    #pragma unroll 1
    for (int jj = 0; jj < 64; ++jj) {
        const int j = (h << 6) + jj;
        f32x4 P = *(const f32x4*)&pts4[j][0];
        // np-exact d2 (bit-identical to the round-2 proven path)
        float dot = __fadd_rn(__fadd_rn(__fmul_rn(Q.x, P.x),
                                        __fmul_rn(Q.y, P.y)),
                              __fmul_rn(Q.z, P.z));
        float dd = __fsub_rn(__fadd_rn(Q.w, P.w), __fmul_rn(2.0f, dot));
        unsigned u = __float_as_uint(dd);
        unsigned key32 = u ^ (((unsigned)(((int)u) >> 31)) | 0x80000000u);
        u64 kk = ((u64)key32 << 32) | (unsigned)j;
        bool ct[16];
        #pragma unroll
        for (int t = 0; t < 16; ++t) ct[t] = bd[t] < kk;
        #pragma unroll
        for (int t = 15; t >= 1; --t)
            bd[t] = ct[t] ? bd[t] : (ct[t - 1] ? kk : bd[t - 1]);
        bd[0] = ct[0] ? bd[0] : kk;
    }

    // ---- phase 2: lane-pair merge; SELF-containing half gets rows first ----
    // Self (j==k) has dd computed bit-exactly 0 -> key strictly minimal -> it is
    // slot 0 of its half's list and that half's rows start at 0 => ROW 0 == SELF
    // (rel exactly (0,0,0); also true for exact-duplicate points). Rows 1..15 go
    // to relbuf; row 0 is synthesized as zeros in phase 3.
    unsigned msk = 0;
    #pragma unroll
    for (int i = 0; i < 16; ++i) {
        u64 o = __shfl_xor(bd[15 - i], 1);   // partner's bd[15-i]
        msk |= (bd[i] < o) ? (1u << i) : 0u;
    }
    const int cnt   = __popc(msk);
    const int hs    = k >> 6;                       // half containing self
    const int rbase = (h == hs) ? 0 : (16 - cnt);   // self-half rows first

    // scale = max norm over selected = sqrt(max d2)  (sqrtf monotone -> bit-identical)
    float m2 = 0.0f;
    #pragma unroll
    for (int i = 0; i < 16; ++i) {
        if (i < cnt) {
            f32x4 P = *(const f32x4*)&pts4[(unsigned)bd[i] & 127u][0];
            float dx = P.x - Q.x, dy = P.y - Q.y, dz = P.z - Q.z;
            m2 = fmaxf(m2, dx * dx + dy * dy + dz * dz);
        }
    }
    m2 = fmaxf(m2, __shfl_xor(m2, 1));
    const float inv = 1.0f / fmaxf(sqrtf(m2), 1e-8f);

    #pragma unroll
    for (int i = 0; i < 16; ++i) {
        if (i < cnt) {
            const int row = rbase + i;
            if (row > 0) {                    // row 0 = self = zeros, not stored
                f32x4 P = *(const f32x4*)&pts4[(unsigned)bd[i] & 127u][0];
                const int t0 = (row - 1) * 3;
                relbuf[(t0 + 0) * 128 + (k ^ ((t0 + 0) & 31))] = (P.x - Q.x) * inv;
                relbuf[(t0 + 1) * 128 + (k ^ ((t0 + 1) & 31))] = (P.y - Q.y) * inv;
                relbuf[(t0 + 2) * 128 + (k ^ ((t0 + 2) & 31))] = (P.z - Q.z) * inv;
            }
        }
    }
    __syncthreads();   // all pts4 reads done -> safe to overwrite with W3 frags

    // ---- phase 2b: fill w3lds (overwrites the pts4 overlay region) ----
    #pragma unroll
    for (int q = 0; q < 4; ++q) {
        const int f = w * 4 + q, n = f >> 1, kb = f & 1;
        bf16x8 v;
        #pragma unroll
        for (int j = 0; j < 8; ++j)
            v[j] = (__bf16)W3[(kb * 32 + g * 8 + j) * 128 + n * 16 + ln];
        w3lds[f][lane] = __builtin_bit_cast(uint4, v);
    }

    // ---- persistent frags: ONLY w2A (16 regs) + b3 (2 regs) stay resident ----
    bf16x8 w2A[4];
    #pragma unroll
    for (int t = 0; t < 4; ++t) {
        const int c = 32 * (t >> 1) + 8 * (ln >> 2) + 4 * (t & 1) + (ln & 3);
        #pragma unroll
        for (int j = 0; j < 8; ++j)
            w2A[t][j] = (__bf16)W2[(g * 8 + j) * 64 + c];
    }
    const float b3r0 = b3[(2 * g) * 16 + ln];
    const float b3r1 = b3[(2 * g + 1) * 16 + ln];
    __syncthreads();

    // ---- phase 3: MFMA MLP, 2 points per iteration, packed-fp32 VALU ----
    // rel reads: lane ln>=1 reads neighbor row ln at t=(ln-1)*3+c; ln==0 -> 0.
    const int lnm = (ln == 0) ? 0 : (ln - 1);
    const float* ra = relbuf + (lnm * 3 + 0) * 128;
    const float* rb = relbuf + (lnm * 3 + 1) * 128;
    const float* rc = relbuf + (lnm * 3 + 2) * 128;
    const int xa = (lnm * 3 + 0) & 31;
    const int xb = (lnm * 3 + 1) & 31;
    const int xc = (lnm * 3 + 2) & 31;
    const float* w1p = wlds + g * 8;          // broadcast per 16-lane group
    const float* b2g = wlds + 128 + 8 * g;

    #pragma unroll 1
    for (int i = 0; i < 16; ++i) {
        const int p0 = w * 32 + 2 * i;
        const int p1 = p0 + 1;
        float r00 = ra[p0 ^ xa], r01 = rb[p0 ^ xb], r02 = rc[p0 ^ xc];
        float r10 = ra[p1 ^ xa], r11 = rb[p1 ^ xb], r12 = rc[p1 ^ xc];
        if (ln == 0) { r00 = 0.f; r01 = 0.f; r02 = 0.f; r10 = 0.f; r11 = 0.f; r12 = 0.f; }
        const f32x2 r00v = {r00, r00}, r01v = {r01, r01}, r02v = {r02, r02};
        const f32x2 r10v = {r10, r10}, r11v = {r11, r11}, r12v = {r12, r12};

        // W1/b1 transient from LDS (broadcast): rows as f32x4 pairs
        f32x4 W0A = *(const f32x4*)&w1p[0],   W0B = *(const f32x4*)&w1p[4];
        f32x4 W1A = *(const f32x4*)&w1p[32],  W1B = *(const f32x4*)&w1p[36];
        f32x4 W2A_ = *(const f32x4*)&w1p[64], W2B_ = *(const f32x4*)&w1p[68];
        f32x4 BA  = *(const f32x4*)&w1p[96],  BB  = *(const f32x4*)&w1p[100];

        // L1 both points: packed over column pairs; cvt_pk words ARE the frags
        unsigned h0w[4], l0w[4], h1w[4], l1w[4];
        #pragma unroll
        for (int jj = 0; jj < 4; ++jj) {
            const int e = 2 * (jj & 1);
            f32x2 w0 = (jj < 2) ? (f32x2){W0A[e], W0A[e+1]} : (f32x2){W0B[e], W0B[e+1]};
            f32x2 w1 = (jj < 2) ? (f32x2){W1A[e], W1A[e+1]} : (f32x2){W1B[e], W1B[e+1]};
            f32x2 w2 = (jj < 2) ? (f32x2){W2A_[e], W2A_[e+1]} : (f32x2){W2B_[e], W2B_[e+1]};
            f32x2 bb = (jj < 2) ? (f32x2){BA[e], BA[e+1]} : (f32x2){BB[e], BB[e+1]};
            f32x2 hv0 = fma2(r02v, w2, fma2(r01v, w1, fma2(r00v, w0, bb)));
            hilo2(relu2(hv0), h0w[jj], l0w[jj]);
            f32x2 hv1 = fma2(r12v, w2, fma2(r11v, w1, fma2(r10v, w0, bb)));
            hilo2(relu2(hv1), h1w[jj], l1w[jj]);
        }
        bf16x8 a1hi0 = frag4(h0w[0], h0w[1], h0w[2], h0w[3]);
        bf16x8 a1lo0 = frag4(l0w[0], l0w[1], l0w[2], l0w[3]);
        bf16x8 a1hi1 = frag4(h1w[0], h1w[1], h1w[2], h1w[3]);
        bf16x8 a1lo1 = frag4(l1w[0], l1w[1], l1w[2], l1w[3]);

        // L2 transposed, both points; b2 C-init transient from LDS (broadcast)
        f32x4 c2_0[4], c2_1[4];
        #pragma unroll
        for (int t = 0; t < 4; ++t) {
            f32x4 acc0 = *(const f32x4*)&b2g[32 * (t >> 1) + 4 * (t & 1)];
            f32x4 acc1 = acc0;
            acc0 = MFMA(w2A[t], a1hi0, acc0);
            acc1 = MFMA(w2A[t], a1hi1, acc1);
            acc0 = MFMA(w2A[t], a1lo0, acc0);
            acc1 = MFMA(w2A[t], a1lo1, acc1);
            c2_0[t] = acc0; c2_1[t] = acc1;
        }

        // relu + hi/lo pack into L3 A-frags (packed pairs)
        unsigned ha0[4], la0[4], hb0[4], lb0[4];
        unsigned ha1[4], la1[4], hb1[4], lb1[4];
        #pragma unroll
        for (int t = 0; t < 2; ++t) {
            f32x2 pA0 = {c2_0[t][0], c2_0[t][1]};
            f32x2 pB0 = {c2_0[t][2], c2_0[t][3]};
            hilo2(relu2(pA0), ha0[2*t],     la0[2*t]);
            hilo2(relu2(pB0), ha0[2*t + 1], la0[2*t + 1]);
            f32x2 pA0b = {c2_0[t+2][0], c2_0[t+2][1]};
            f32x2 pB0b = {c2_0[t+2][2], c2_0[t+2][3]};
            hilo2(relu2(pA0b), hb0[2*t],     lb0[2*t]);
            hilo2(relu2(pB0b), hb0[2*t + 1], lb0[2*t + 1]);
            f32x2 pA1 = {c2_1[t][0], c2_1[t][1]};
            f32x2 pB1 = {c2_1[t][2], c2_1[t][3]};
            hilo2(relu2(pA1), ha1[2*t],     la1[2*t]);
            hilo2(relu2(pB1), ha1[2*t + 1], la1[2*t + 1]);
            f32x2 pA1b = {c2_1[t+2][0], c2_1[t+2][1]};
            f32x2 pB1b = {c2_1[t+2][2], c2_1[t+2][3]};
            hilo2(relu2(pA1b), hb1[2*t],     lb1[2*t]);
            hilo2(relu2(pB1b), hb1[2*t + 1], lb1[2*t + 1]);
        }
        bf16x8 h30a = frag4(ha0[0], ha0[1], ha0[2], ha0[3]);
        bf16x8 l30a = frag4(la0[0], la0[1], la0[2], la0[3]);
        bf16x8 h30b = frag4(hb0[0], hb0[1], hb0[2], hb0[3]);
        bf16x8 l30b = frag4(lb0[0], lb0[1], lb0[2], lb0[3]);
        bf16x8 h31a = frag4(ha1[0], ha1[1], ha1[2], ha1[3]);
        bf16x8 l31a = frag4(la1[0], la1[1], la1[2], la1[3]);
        bf16x8 h31b = frag4(hb1[0], hb1[1], hb1[2], hb1[3]);
        bf16x8 l31b = frag4(lb1[0], lb1[1], lb1[2], lb1[3]);

        // L3: 4 steps x 2 tiles, W3 frags read once, used by both points
        float s0_0 = 0.f, s1_0 = 0.f, s0_1 = 0.f, s1_1 = 0.f;
        #pragma unroll
        for (int nn = 0; nn < 4; ++nn) {
            bf16x8 c0a = __builtin_bit_cast(bf16x8, w3lds[nn * 4 + 0][lane]);
            bf16x8 c0b = __builtin_bit_cast(bf16x8, w3lds[nn * 4 + 1][lane]);
            bf16x8 c1a = __builtin_bit_cast(bf16x8, w3lds[nn * 4 + 2][lane]);
            bf16x8 c1b = __builtin_bit_cast(bf16x8, w3lds[nn * 4 + 3][lane]);
            f32x4 a00 = {0,0,0,0}, a01 = {0,0,0,0}, a10 = {0,0,0,0}, a11 = {0,0,0,0};
            a00 = MFMA(h30a, c0a, a00); a00 = MFMA(h30b, c0b, a00);
            a00 = MFMA(l30a, c0a, a00); a00 = MFMA(l30b, c0b, a00);
            a01 = MFMA(h30a, c1a, a01); a01 = MFMA(h30b, c1b, a01);
            a01 = MFMA(l30a, c1a, a01); a01 = MFMA(l30b, c1b, a01);
            a10 = MFMA(h31a, c0a, a10); a10 = MFMA(h31b, c0b, a10);
            a10 = MFMA(l31a, c0a, a10); a10 = MFMA(l31b, c0b, a10);
            a11 = MFMA(h31a, c1a, a11); a11 = MFMA(h31b, c1b, a11);
            a11 = MFMA(l31a, c1a, a11); a11 = MFMA(l31b, c1b, a11);
            f32x2 m00 = __builtin_elementwise_max((f32x2){a00[0], a00[1]}, (f32x2){a00[2], a00[3]});
            float v00 = fmaxf(m00[0], m00[1]);
            v00 = fmaxf(v00, __shfl_xor(v00, 16)); v00 = fmaxf(v00, __shfl_xor(v00, 32));
            f32x2 m01 = __builtin_elementwise_max((f32x2){a01[0], a01[1]}, (f32x2){a01[2], a01[3]});
            float v01 = fmaxf(m01[0], m01[1]);
            v01 = fmaxf(v01, __shfl_xor(v01, 16)); v01 = fmaxf(v01, __shfl_xor(v01, 32));
            f32x2 m10 = __builtin_elementwise_max((f32x2){a10[0], a10[1]}, (f32x2){a10[2], a10[3]});
            float v10 = fmaxf(m10[0], m10[1]);
            v10 = fmaxf(v10, __shfl_xor(v10, 16)); v10 = fmaxf(v10, __shfl_xor(v10, 32));
            f32x2 m11 = __builtin_elementwise_max((f32x2){a11[0], a11[1]}, (f32x2){a11[2], a11[3]});
            float v11 = fmaxf(m11[0], m11[1]);
            v11 = fmaxf(v11, __shfl_xor(v11, 16)); v11 = fmaxf(v11, __shfl_xor(v11, 32));
            if (nn == g) { s0_0 = v00; s1_0 = v01; s0_1 = v10; s1_1 = v11; }
        }
        float* o0 = out + ((size_t)(m * 128 + p0) << 7);
        float* o1 = out + ((size_t)(m * 128 + p1) << 7);
        o0[(2 * g) * 16 + ln]     = s0_0 + b3r0;
        o0[(2 * g + 1) * 16 + ln] = s1_0 + b3r1;
        o1[(2 * g) * 16 + ln]     = s0_1 + b3r0;
        o1[(2 * g + 1) * 16 + ln] = s1_1 + b3r1;
    }
}

extern "C" void kernel_launch(void* const* d_in, const int* in_sizes, int n_in,
                              void* d_out, int out_size, void* d_ws, size_t ws_size,
                              hipStream_t stream) {
    const float* windows = (const float*)d_in[0];
    const float* W1 = (const float*)d_in[1];
    const float* b1 = (const float*)d_in[2];
    const float* W2 = (const float*)d_in[3];
    const float* b2 = (const float*)d_in[4];
    const float* W3 = (const float*)d_in[5];
    const float* b3 = (const float*)d_in[6];
    float* out = (float*)d_out;
    hipLaunchKernelGGL(miniemb_kernel, dim3(1024), dim3(256), 0, stream,
                       windows, W1, b1, W2, b2, W3, b3, out);
}

// Round 9
// 224.031 us; speedup vs baseline: 1.2062x; 1.2062x over previous
//
#include <hip/hip_runtime.h>

typedef __bf16 bf16x8 __attribute__((ext_vector_type(8)));
typedef __bf16 bf16x2 __attribute__((ext_vector_type(2)));
typedef float  f32x4  __attribute__((ext_vector_type(4)));
typedef float  f32x2  __attribute__((ext_vector_type(2)));
typedef unsigned long long u64;

#define MFMA(a, b, c) __builtin_amdgcn_mfma_f32_16x16x32_bf16((a), (b), (c), 0, 0, 0)

// Packed fp32 helpers -> v_pk_fma_f32 / v_pk_max_f32 (bit-exact per element).
__device__ __forceinline__ f32x2 fma2(f32x2 a, f32x2 b, f32x2 c) {
    return __builtin_elementwise_fma(a, b, c);
}
__device__ __forceinline__ f32x2 relu2(f32x2 a) {
    f32x2 z = {0.0f, 0.0f};
    return __builtin_elementwise_max(a, z);
}
// Double-bf16 (hi/lo) split of a packed f32 pair; word layout = MFMA frag word.
__device__ __forceinline__ void hilo2(f32x2 h, unsigned& hiw, unsigned& low) {
    bf16x2 hb = __builtin_convertvector(h, bf16x2);
    unsigned hw = __builtin_bit_cast(unsigned, hb);
    f32x2 hf;
    hf[0] = __builtin_bit_cast(float, hw << 16);
    hf[1] = __builtin_bit_cast(float, hw & 0xFFFF0000u);
    f32x2 lo = h - hf;
    bf16x2 lb = __builtin_convertvector(lo, bf16x2);
    hiw = hw;
    low = __builtin_bit_cast(unsigned, lb);
}
__device__ __forceinline__ bf16x8 frag4(unsigned w0, unsigned w1, unsigned w2, unsigned w3) {
    uint4 u; u.x = w0; u.y = w1; u.z = w2; u.w = w3;
    return __builtin_bit_cast(bf16x8, u);
}

// __launch_bounds__(256, 3): combined VGPR+AGPR budget 170 -> 3 waves/SIMD.
// History: (256,4) [128 combined] forces 64 arch VGPRs -> heavy spill (r1: 604MB,
// r8: 462MB FETCH). Plain bounds -> combined in (170,256] -> 2 waves/SIMD, 20%
// occupancy. 170 needs only a ~10-40 reg shave from natural -> expect little/no
// spill. Tripwire: FETCH_SIZE >> 1.2 MB means spill -> revert to plain bounds.
__global__ __launch_bounds__(256, 3) void miniemb_kernel(
    const float* __restrict__ windows,
    const float* __restrict__ W1, const float* __restrict__ b1,
    const float* __restrict__ W2, const float* __restrict__ b2,
    const float* __restrict__ W3, const float* __restrict__ b3,
    float* __restrict__ out)
{
    // LDS total = 24576 + 16384 = 40960 B.
    __shared__ float relbuf[48 * 128];   // XOR-swizzled: word = t*128 + (p ^ (t&31))
    __shared__ uint4 w3lds[16][64];      // W3 B-frags; first 2 KiB doubles as pts4 in ph1-2

    float (*pts4)[4] = reinterpret_cast<float(*)[4]>(&w3lds[0][0]);

    const int m    = blockIdx.x;
    const int tid  = threadIdx.x;
    const int w    = tid >> 6;
    const int lane = tid & 63;
    const int g    = lane >> 4;
    const int ln   = lane & 15;

    // ---- phase 0: stage pts4 (x,y,z,|p|^2) -- W3 fill deferred to after phase 2 ----
    const float* wm = windows + (size_t)m * 128 * 3;
    if (tid < 128) {
        float x = wm[tid * 3], y = wm[tid * 3 + 1], z = wm[tid * 3 + 2];
        float s = __fadd_rn(__fadd_rn(__fmul_rn(x, x), __fmul_rn(y, y)),
                            __fmul_rn(z, z));
        f32x4 P = {x, y, z, s};
        *(f32x4*)&pts4[tid][0] = P;
    }
    __syncthreads();

    // ---- phase 1: kNN scan, 2 threads per point, sorted insert (breadth-wise) ----
    const int k = tid >> 1;      // point
    const int h = tid & 1;       // half
    f32x4 Q = *(const f32x4*)&pts4[k][0];
    u64 bd[16];
    #pragma unroll
    for (int t = 0; t < 16; ++t) bd[t] = ~0ull;
    #pragma unroll 1
    for (int jj = 0; jj < 64; ++jj) {
        const int j = (h << 6) + jj;
        f32x4 P = *(const f32x4*)&pts4[j][0];
        // np-exact d2 (bit-identical to the round-2 proven path)
        float dot = __fadd_rn(__fadd_rn(__fmul_rn(Q.x, P.x),
                                        __fmul_rn(Q.y, P.y)),
                              __fmul_rn(Q.z, P.z));
        float dd = __fsub_rn(__fadd_rn(Q.w, P.w), __fmul_rn(2.0f, dot));
        unsigned u = __float_as_uint(dd);
        unsigned key32 = u ^ (((unsigned)(((int)u) >> 31)) | 0x80000000u);
        u64 kk = ((u64)key32 << 32) | (unsigned)j;
        bool ct[16];
        #pragma unroll
        for (int t = 0; t < 16; ++t) ct[t] = bd[t] < kk;
        #pragma unroll
        for (int t = 15; t >= 1; --t)
            bd[t] = ct[t] ? bd[t] : (ct[t - 1] ? kk : bd[t - 1]);
        bd[0] = ct[0] ? bd[0] : kk;
    }

    // ---- phase 2: lane-pair merge, partner values STREAMED via shuffle ----
    unsigned msk = 0;
    #pragma unroll
    for (int i = 0; i < 16; ++i) {
        u64 o = __shfl_xor(bd[15 - i], 1);   // partner's bd[15-i]
        msk |= (bd[i] < o) ? (1u << i) : 0u;
    }
    const int cnt   = __popc(msk);
    const int rbase = h ? (16 - cnt) : 0;    // A rows: 0..cA-1, B rows: cA..15

    // scale = max norm over selected = sqrt(max d2)  (sqrtf monotone -> bit-identical)
    float m2 = 0.0f;
    #pragma unroll
    for (int i = 0; i < 16; ++i) {
        if (i < cnt) {
            f32x4 P = *(const f32x4*)&pts4[(unsigned)bd[i] & 127u][0];
            float dx = P.x - Q.x, dy = P.y - Q.y, dz = P.z - Q.z;
            m2 = fmaxf(m2, dx * dx + dy * dy + dz * dz);
        }
    }
    m2 = fmaxf(m2, __shfl_xor(m2, 1));
    const float inv = 1.0f / fmaxf(sqrtf(m2), 1e-8f);

    #pragma unroll
    for (int i = 0; i < 16; ++i) {
        if (i < cnt) {
            f32x4 P = *(const f32x4*)&pts4[(unsigned)bd[i] & 127u][0];
            const int t0 = (rbase + i) * 3;
            relbuf[(t0 + 0) * 128 + (k ^ ((t0 + 0) & 31))] = (P.x - Q.x) * inv;
            relbuf[(t0 + 1) * 128 + (k ^ ((t0 + 1) & 31))] = (P.y - Q.y) * inv;
            relbuf[(t0 + 2) * 128 + (k ^ ((t0 + 2) & 31))] = (P.z - Q.z) * inv;
        }
    }
    __syncthreads();   // all pts4 reads done -> safe to overwrite with W3 frags

    // ---- phase 2b: fill w3lds (overwrites the pts4 overlay region) ----
    #pragma unroll
    for (int q = 0; q < 4; ++q) {
        const int f = w * 4 + q, n = f >> 1, kb = f & 1;
        bf16x8 v;
        #pragma unroll
        for (int j = 0; j < 8; ++j)
            v[j] = (__bf16)W3[(kb * 32 + g * 8 + j) * 128 + n * 16 + ln];
        w3lds[f][lane] = __builtin_bit_cast(uint4, v);
    }

    // ---- persistent weight fragments (after kNN: caps register pressure) ----
    bf16x8 w2A[4];
    #pragma unroll
    for (int t = 0; t < 4; ++t) {
        const int c = 32 * (t >> 1) + 8 * (ln >> 2) + 4 * (t & 1) + (ln & 3);
        #pragma unroll
        for (int j = 0; j < 8; ++j)
            w2A[t][j] = (__bf16)W2[(g * 8 + j) * 64 + c];
    }
    float b2p[16];
    #pragma unroll
    for (int t = 0; t < 4; ++t)
        #pragma unroll
        for (int r = 0; r < 4; ++r)
            b2p[t * 4 + r] = b2[32 * (t >> 1) + 8 * g + 4 * (t & 1) + r];
    // W1/b1 as packed f32x2 over column pairs (c = g*8 + 2*jj + e)
    f32x2 w1v0[4], w1v1[4], w1v2[4], b1v[4];
    #pragma unroll
    for (int jj = 0; jj < 4; ++jj) {
        const int c = g * 8 + 2 * jj;
        w1v0[jj] = *(const f32x2*)&W1[c];
        w1v1[jj] = *(const f32x2*)&W1[32 + c];
        w1v2[jj] = *(const f32x2*)&W1[64 + c];
        b1v[jj]  = *(const f32x2*)&b1[c];
    }
    const float b3r0 = b3[(2 * g) * 16 + ln];
    const float b3r1 = b3[(2 * g + 1) * 16 + ln];
    __syncthreads();

    // ---- phase 3: MFMA MLP, 2 points per iteration, packed-fp32 VALU ----
    const float* ra = relbuf + (ln * 3 + 0) * 128;
    const float* rb = relbuf + (ln * 3 + 1) * 128;
    const float* rc = relbuf + (ln * 3 + 2) * 128;
    const int xa = (ln * 3 + 0) & 31;
    const int xb = (ln * 3 + 1) & 31;
    const int xc = (ln * 3 + 2) & 31;

    #pragma unroll 1
    for (int i = 0; i < 16; ++i) {
        const int p0 = w * 32 + 2 * i;
        const int p1 = p0 + 1;
        const float r00 = ra[p0 ^ xa], r01 = rb[p0 ^ xb], r02 = rc[p0 ^ xc];
        const float r10 = ra[p1 ^ xa], r11 = rb[p1 ^ xb], r12 = rc[p1 ^ xc];
        const f32x2 r00v = {r00, r00}, r01v = {r01, r01}, r02v = {r02, r02};
        const f32x2 r10v = {r10, r10}, r11v = {r11, r11}, r12v = {r12, r12};

        // L1 both points: packed over column pairs; cvt_pk words ARE the frags
        unsigned h0w[4], l0w[4], h1w[4], l1w[4];
        #pragma unroll
        for (int jj = 0; jj < 4; ++jj) {
            f32x2 hv0 = fma2(r02v, w1v2[jj], fma2(r01v, w1v1[jj], fma2(r00v, w1v0[jj], b1v[jj])));
            hilo2(relu2(hv0), h0w[jj], l0w[jj]);
            f32x2 hv1 = fma2(r12v, w1v2[jj], fma2(r11v, w1v1[jj], fma2(r10v, w1v0[jj], b1v[jj])));
            hilo2(relu2(hv1), h1w[jj], l1w[jj]);
        }
        bf16x8 a1hi0 = frag4(h0w[0], h0w[1], h0w[2], h0w[3]);
        bf16x8 a1lo0 = frag4(l0w[0], l0w[1], l0w[2], l0w[3]);
        bf16x8 a1hi1 = frag4(h1w[0], h1w[1], h1w[2], h1w[3]);
        bf16x8 a1lo1 = frag4(l1w[0], l1w[1], l1w[2], l1w[3]);

        // L2 transposed, both points
        f32x4 c2_0[4], c2_1[4];
        #pragma unroll
        for (int t = 0; t < 4; ++t) {
            f32x4 acc0 = {b2p[t*4+0], b2p[t*4+1], b2p[t*4+2], b2p[t*4+3]};
            f32x4 acc1 = acc0;
            acc0 = MFMA(w2A[t], a1hi0, acc0);
            acc1 = MFMA(w2A[t], a1hi1, acc1);
            acc0 = MFMA(w2A[t], a1lo0, acc0);
            acc1 = MFMA(w2A[t], a1lo1, acc1);
            c2_0[t] = acc0; c2_1[t] = acc1;
        }

        // relu + hi/lo pack into L3 A-frags (packed pairs; word jj = elems 2jj,2jj+1)
        unsigned ha0[4], la0[4], hb0[4], lb0[4];   // point0: t<2 -> "a", t>=2 -> "b"
        unsigned ha1[4], la1[4], hb1[4], lb1[4];   // point1
        #pragma unroll
        for (int t = 0; t < 2; ++t) {
            f32x2 pA0 = {c2_0[t][0], c2_0[t][1]};
            f32x2 pB0 = {c2_0[t][2], c2_0[t][3]};
            hilo2(relu2(pA0), ha0[2*t],     la0[2*t]);
            hilo2(relu2(pB0), ha0[2*t + 1], la0[2*t + 1]);
            f32x2 pA0b = {c2_0[t+2][0], c2_0[t+2][1]};
            f32x2 pB0b = {c2_0[t+2][2], c2_0[t+2][3]};
            hilo2(relu2(pA0b), hb0[2*t],     lb0[2*t]);
            hilo2(relu2(pB0b), hb0[2*t + 1], lb0[2*t + 1]);
            f32x2 pA1 = {c2_1[t][0], c2_1[t][1]};
            f32x2 pB1 = {c2_1[t][2], c2_1[t][3]};
            hilo2(relu2(pA1), ha1[2*t],     la1[2*t]);
            hilo2(relu2(pB1), ha1[2*t + 1], la1[2*t + 1]);
            f32x2 pA1b = {c2_1[t+2][0], c2_1[t+2][1]};
            f32x2 pB1b = {c2_1[t+2][2], c2_1[t+2][3]};
            hilo2(relu2(pA1b), hb1[2*t],     lb1[2*t]);
            hilo2(relu2(pB1b), hb1[2*t + 1], lb1[2*t + 1]);
        }
        bf16x8 h30a = frag4(ha0[0], ha0[1], ha0[2], ha0[3]);
        bf16x8 l30a = frag4(la0[0], la0[1], la0[2], la0[3]);
        bf16x8 h30b = frag4(hb0[0], hb0[1], hb0[2], hb0[3]);
        bf16x8 l30b = frag4(lb0[0], lb0[1], lb0[2], lb0[3]);
        bf16x8 h31a = frag4(ha1[0], ha1[1], ha1[2], ha1[3]);
        bf16x8 l31a = frag4(la1[0], la1[1], la1[2], la1[3]);
        bf16x8 h31b = frag4(hb1[0], hb1[1], hb1[2], hb1[3]);
        bf16x8 l31b = frag4(lb1[0], lb1[1], lb1[2], lb1[3]);

        // L3: 4 steps x 2 tiles, W3 frags read once, used by both points
        float s0_0 = 0.f, s1_0 = 0.f, s0_1 = 0.f, s1_1 = 0.f;
        #pragma unroll
        for (int nn = 0; nn < 4; ++nn) {
            bf16x8 c0a = __builtin_bit_cast(bf16x8, w3lds[nn * 4 + 0][lane]);
            bf16x8 c0b = __builtin_bit_cast(bf16x8, w3lds[nn * 4 + 1][lane]);
            bf16x8 c1a = __builtin_bit_cast(bf16x8, w3lds[nn * 4 + 2][lane]);
            bf16x8 c1b = __builtin_bit_cast(bf16x8, w3lds[nn * 4 + 3][lane]);
            f32x4 a00 = {0,0,0,0}, a01 = {0,0,0,0}, a10 = {0,0,0,0}, a11 = {0,0,0,0};
            a00 = MFMA(h30a, c0a, a00); a00 = MFMA(h30b, c0b, a00);
            a00 = MFMA(l30a, c0a, a00); a00 = MFMA(l30b, c0b, a00);
            a01 = MFMA(h30a, c1a, a01); a01 = MFMA(h30b, c1b, a01);
            a01 = MFMA(l30a, c1a, a01); a01 = MFMA(l30b, c1b, a01);
            a10 = MFMA(h31a, c0a, a10); a10 = MFMA(h31b, c0b, a10);
            a10 = MFMA(l31a, c0a, a10); a10 = MFMA(l31b, c0b, a10);
            a11 = MFMA(h31a, c1a, a11); a11 = MFMA(h31b, c1b, a11);
            a11 = MFMA(l31a, c1a, a11); a11 = MFMA(l31b, c1b, a11);
            f32x2 m00 = __builtin_elementwise_max((f32x2){a00[0], a00[1]}, (f32x2){a00[2], a00[3]});
            float v00 = fmaxf(m00[0], m00[1]);
            v00 = fmaxf(v00, __shfl_xor(v00, 16)); v00 = fmaxf(v00, __shfl_xor(v00, 32));
            f32x2 m01 = __builtin_elementwise_max((f32x2){a01[0], a01[1]}, (f32x2){a01[2], a01[3]});
            float v01 = fmaxf(m01[0], m01[1]);
            v01 = fmaxf(v01, __shfl_xor(v01, 16)); v01 = fmaxf(v01, __shfl_xor(v01, 32));
            f32x2 m10 = __builtin_elementwise_max((f32x2){a10[0], a10[1]}, (f32x2){a10[2], a10[3]});
            float v10 = fmaxf(m10[0], m10[1]);
            v10 = fmaxf(v10, __shfl_xor(v10, 16)); v10 = fmaxf(v10, __shfl_xor(v10, 32));
            f32x2 m11 = __builtin_elementwise_max((f32x2){a11[0], a11[1]}, (f32x2){a11[2], a11[3]});
            float v11 = fmaxf(m11[0], m11[1]);
            v11 = fmaxf(v11, __shfl_xor(v11, 16)); v11 = fmaxf(v11, __shfl_xor(v11, 32));
            if (nn == g) { s0_0 = v00; s1_0 = v01; s0_1 = v10; s1_1 = v11; }
        }
        float* o0 = out + ((size_t)(m * 128 + p0) << 7);
        float* o1 = out + ((size_t)(m * 128 + p1) << 7);
        o0[(2 * g) * 16 + ln]     = s0_0 + b3r0;
        o0[(2 * g + 1) * 16 + ln] = s1_0 + b3r1;
        o1[(2 * g) * 16 + ln]     = s0_1 + b3r0;
        o1[(2 * g + 1) * 16 + ln] = s1_1 + b3r1;
    }
}

extern "C" void kernel_launch(void* const* d_in, const int* in_sizes, int n_in,
                              void* d_out, int out_size, void* d_ws, size_t ws_size,
                              hipStream_t stream) {
    const float* windows = (const float*)d_in[0];
    const float* W1 = (const float*)d_in[1];
    const float* b1 = (const float*)d_in[2];
    const float* W2 = (const float*)d_in[3];
    const float* b2 = (const float*)d_in[4];
    const float* W3 = (const float*)d_in[5];
    const float* b3 = (const float*)d_in[6];
    float* out = (float*)d_out;
    hipLaunchKernelGGL(miniemb_kernel, dim3(1024), dim3(256), 0, stream,
                       windows, W1, b1, W2, b2, W3, b3, out);
}

// Round 10
// 221.203 us; speedup vs baseline: 1.2216x; 1.0128x over previous
//
#include <hip/hip_runtime.h>

typedef __bf16 bf16x8 __attribute__((ext_vector_type(8)));
typedef __bf16 bf16x2 __attribute__((ext_vector_type(2)));
typedef float  f32x4  __attribute__((ext_vector_type(4)));
typedef float  f32x2  __attribute__((ext_vector_type(2)));
typedef unsigned long long u64;

#define MFMA(a, b, c) __builtin_amdgcn_mfma_f32_16x16x32_bf16((a), (b), (c), 0, 0, 0)

// Packed fp32 helpers -> v_pk_fma_f32 / v_pk_max_f32 (bit-exact per element).
__device__ __forceinline__ f32x2 fma2(f32x2 a, f32x2 b, f32x2 c) {
    return __builtin_elementwise_fma(a, b, c);
}
__device__ __forceinline__ f32x2 relu2(f32x2 a) {
    f32x2 z = {0.0f, 0.0f};
    return __builtin_elementwise_max(a, z);
}
// Double-bf16 (hi/lo) split of a packed f32 pair; word layout = MFMA frag word.
__device__ __forceinline__ void hilo2(f32x2 h, unsigned& hiw, unsigned& low) {
    bf16x2 hb = __builtin_convertvector(h, bf16x2);
    unsigned hw = __builtin_bit_cast(unsigned, hb);
    f32x2 hf;
    hf[0] = __builtin_bit_cast(float, hw << 16);
    hf[1] = __builtin_bit_cast(float, hw & 0xFFFF0000u);
    f32x2 lo = h - hf;
    bf16x2 lb = __builtin_convertvector(lo, bf16x2);
    hiw = hw;
    low = __builtin_bit_cast(unsigned, lb);
}
__device__ __forceinline__ bf16x8 frag4(unsigned w0, unsigned w1, unsigned w2, unsigned w3) {
    uint4 u; u.x = w0; u.y = w1; u.z = w2; u.w = w3;
    return __builtin_bit_cast(bf16x8, u);
}

// __launch_bounds__(256, 3): combined budget 170 -> 3 waves/SIMD.
// Round 9 showed (256,3) alone spills ~25 dwords/thread (FETCH 12.6MB, net LOSS
// vs plain). This version removes ~32 persistent VGPRs of demand first:
// w2A frags (16) -> w2lds LDS table; b2p (16) -> b2lds. Tripwire: FETCH >> 1.3MB
// means still spilling -> revert to plain bounds keeping the LDS moves.
__global__ __launch_bounds__(256, 3) void miniemb_kernel(
    const float* __restrict__ windows,
    const float* __restrict__ W1, const float* __restrict__ b1,
    const float* __restrict__ W2, const float* __restrict__ b2,
    const float* __restrict__ W3, const float* __restrict__ b3,
    float* __restrict__ out)
{
    // LDS total = 24576 + 16384 + 4096 + 256 = 45312 B -> 3 blocks/CU (<=54613).
    __shared__ float relbuf[48 * 128];   // XOR-swizzled: word = t*128 + (p ^ (t&31))
    __shared__ uint4 w3lds[16][64];      // W3 B-frags; first 2 KiB doubles as pts4 in ph1-2
    __shared__ uint4 w2lds[4][64];       // W2 A-frags [t][lane]
    __shared__ float b2lds[64];

    float (*pts4)[4] = reinterpret_cast<float(*)[4]>(&w3lds[0][0]);

    const int m    = blockIdx.x;
    const int tid  = threadIdx.x;
    const int w    = tid >> 6;
    const int lane = tid & 63;
    const int g    = lane >> 4;
    const int ln   = lane & 15;

    // ---- phase 0: stage pts4 (x,y,z,|p|^2) + b2 ----
    const float* wm = windows + (size_t)m * 128 * 3;
    if (tid < 128) {
        float x = wm[tid * 3], y = wm[tid * 3 + 1], z = wm[tid * 3 + 2];
        float s = __fadd_rn(__fadd_rn(__fmul_rn(x, x), __fmul_rn(y, y)),
                            __fmul_rn(z, z));
        f32x4 P = {x, y, z, s};
        *(f32x4*)&pts4[tid][0] = P;
    }
    if (tid < 64) b2lds[tid] = b2[tid];
    __syncthreads();

    // ---- phase 1: kNN scan, 2 threads per point, sorted insert (breadth-wise) ----
    const int k = tid >> 1;      // point
    const int h = tid & 1;       // half
    f32x4 Q = *(const f32x4*)&pts4[k][0];
    u64 bd[16];
    #pragma unroll
    for (int t = 0; t < 16; ++t) bd[t] = ~0ull;
    #pragma unroll 1
    for (int jj = 0; jj < 64; ++jj) {
        const int j = (h << 6) + jj;
        f32x4 P = *(const f32x4*)&pts4[j][0];
        // np-exact d2 (bit-identical to the round-2 proven path)
        float dot = __fadd_rn(__fadd_rn(__fmul_rn(Q.x, P.x),
                                        __fmul_rn(Q.y, P.y)),
                              __fmul_rn(Q.z, P.z));
        float dd = __fsub_rn(__fadd_rn(Q.w, P.w), __fmul_rn(2.0f, dot));
        unsigned u = __float_as_uint(dd);
        unsigned key32 = u ^ (((unsigned)(((int)u) >> 31)) | 0x80000000u);
        u64 kk = ((u64)key32 << 32) | (unsigned)j;
        bool ct[16];
        #pragma unroll
        for (int t = 0; t < 16; ++t) ct[t] = bd[t] < kk;
        #pragma unroll
        for (int t = 15; t >= 1; --t)
            bd[t] = ct[t] ? bd[t] : (ct[t - 1] ? kk : bd[t - 1]);
        bd[0] = ct[0] ? bd[0] : kk;
    }

    // ---- phase 2: lane-pair merge, partner values STREAMED via shuffle ----
    unsigned msk = 0;
    #pragma unroll
    for (int i = 0; i < 16; ++i) {
        u64 o = __shfl_xor(bd[15 - i], 1);   // partner's bd[15-i]
        msk |= (bd[i] < o) ? (1u << i) : 0u;
    }
    const int cnt   = __popc(msk);
    const int rbase = h ? (16 - cnt) : 0;    // A rows: 0..cA-1, B rows: cA..15

    // scale = max norm over selected = sqrt(max d2)  (sqrtf monotone -> bit-identical)
    float m2 = 0.0f;
    #pragma unroll
    for (int i = 0; i < 16; ++i) {
        if (i < cnt) {
            f32x4 P = *(const f32x4*)&pts4[(unsigned)bd[i] & 127u][0];
            float dx = P.x - Q.x, dy = P.y - Q.y, dz = P.z - Q.z;
            m2 = fmaxf(m2, dx * dx + dy * dy + dz * dz);
        }
    }
    m2 = fmaxf(m2, __shfl_xor(m2, 1));
    const float inv = 1.0f / fmaxf(sqrtf(m2), 1e-8f);

    #pragma unroll
    for (int i = 0; i < 16; ++i) {
        if (i < cnt) {
            f32x4 P = *(const f32x4*)&pts4[(unsigned)bd[i] & 127u][0];
            const int t0 = (rbase + i) * 3;
            relbuf[(t0 + 0) * 128 + (k ^ ((t0 + 0) & 31))] = (P.x - Q.x) * inv;
            relbuf[(t0 + 1) * 128 + (k ^ ((t0 + 1) & 31))] = (P.y - Q.y) * inv;
            relbuf[(t0 + 2) * 128 + (k ^ ((t0 + 2) & 31))] = (P.z - Q.z) * inv;
        }
    }
    __syncthreads();   // all pts4 reads done -> safe to overwrite with W3 frags

    // ---- phase 2b: fill w3lds (overwrites pts4 overlay) + w2lds frag table ----
    #pragma unroll
    for (int q = 0; q < 4; ++q) {
        const int f = w * 4 + q, n = f >> 1, kb = f & 1;
        bf16x8 v;
        #pragma unroll
        for (int j = 0; j < 8; ++j)
            v[j] = (__bf16)W3[(kb * 32 + g * 8 + j) * 128 + n * 16 + ln];
        w3lds[f][lane] = __builtin_bit_cast(uint4, v);
    }
    {
        // wave w stages w2lds[w][lane]: frag value depends only on (t=w, lane)
        const int c = 32 * (w >> 1) + 8 * (ln >> 2) + 4 * (w & 1) + (ln & 3);
        bf16x8 v;
        #pragma unroll
        for (int j = 0; j < 8; ++j)
            v[j] = (__bf16)W2[(g * 8 + j) * 64 + c];
        w2lds[w][lane] = __builtin_bit_cast(uint4, v);
    }

    // ---- persistent: only W1/b1 packed pairs + b3 stay in registers ----
    f32x2 w1v0[4], w1v1[4], w1v2[4], b1v[4];
    #pragma unroll
    for (int jj = 0; jj < 4; ++jj) {
        const int c = g * 8 + 2 * jj;
        w1v0[jj] = *(const f32x2*)&W1[c];
        w1v1[jj] = *(const f32x2*)&W1[32 + c];
        w1v2[jj] = *(const f32x2*)&W1[64 + c];
        b1v[jj]  = *(const f32x2*)&b1[c];
    }
    const float b3r0 = b3[(2 * g) * 16 + ln];
    const float b3r1 = b3[(2 * g + 1) * 16 + ln];
    __syncthreads();

    // ---- phase 3: MFMA MLP, 2 points per iteration, packed-fp32 VALU ----
    const float* ra = relbuf + (ln * 3 + 0) * 128;
    const float* rb = relbuf + (ln * 3 + 1) * 128;
    const float* rc = relbuf + (ln * 3 + 2) * 128;
    const int xa = (ln * 3 + 0) & 31;
    const int xb = (ln * 3 + 1) & 31;
    const int xc = (ln * 3 + 2) & 31;

    #pragma unroll 1
    for (int i = 0; i < 16; ++i) {
        const int p0 = w * 32 + 2 * i;
        const int p1 = p0 + 1;
        const float r00 = ra[p0 ^ xa], r01 = rb[p0 ^ xb], r02 = rc[p0 ^ xc];
        const float r10 = ra[p1 ^ xa], r11 = rb[p1 ^ xb], r12 = rc[p1 ^ xc];
        const f32x2 r00v = {r00, r00}, r01v = {r01, r01}, r02v = {r02, r02};
        const f32x2 r10v = {r10, r10}, r11v = {r11, r11}, r12v = {r12, r12};

        // L1 both points: packed over column pairs; cvt_pk words ARE the frags
        unsigned h0w[4], l0w[4], h1w[4], l1w[4];
        #pragma unroll
        for (int jj = 0; jj < 4; ++jj) {
            f32x2 hv0 = fma2(r02v, w1v2[jj], fma2(r01v, w1v1[jj], fma2(r00v, w1v0[jj], b1v[jj])));
            hilo2(relu2(hv0), h0w[jj], l0w[jj]);
            f32x2 hv1 = fma2(r12v, w1v2[jj], fma2(r11v, w1v1[jj], fma2(r10v, w1v0[jj], b1v[jj])));
            hilo2(relu2(hv1), h1w[jj], l1w[jj]);
        }
        bf16x8 a1hi0 = frag4(h0w[0], h0w[1], h0w[2], h0w[3]);
        bf16x8 a1lo0 = frag4(l0w[0], l0w[1], l0w[2], l0w[3]);
        bf16x8 a1hi1 = frag4(h1w[0], h1w[1], h1w[2], h1w[3]);
        bf16x8 a1lo1 = frag4(l1w[0], l1w[1], l1w[2], l1w[3]);

        // L2 transposed, both points; W2 frag + b2 C-init from LDS (broadcast)
        f32x4 c2_0[4], c2_1[4];
        #pragma unroll
        for (int t = 0; t < 4; ++t) {
            bf16x8 w2f = __builtin_bit_cast(bf16x8, w2lds[t][lane]);
            f32x4 acc0 = *(const f32x4*)&b2lds[32 * (t >> 1) + 8 * g + 4 * (t & 1)];
            f32x4 acc1 = acc0;
            acc0 = MFMA(w2f, a1hi0, acc0);
            acc1 = MFMA(w2f, a1hi1, acc1);
            acc0 = MFMA(w2f, a1lo0, acc0);
            acc1 = MFMA(w2f, a1lo1, acc1);
            c2_0[t] = acc0; c2_1[t] = acc1;
        }

        // relu + hi/lo pack into L3 A-frags (packed pairs; word jj = elems 2jj,2jj+1)
        unsigned ha0[4], la0[4], hb0[4], lb0[4];   // point0: t<2 -> "a", t>=2 -> "b"
        unsigned ha1[4], la1[4], hb1[4], lb1[4];   // point1
        #pragma unroll
        for (int t = 0; t < 2; ++t) {
            f32x2 pA0 = {c2_0[t][0], c2_0[t][1]};
            f32x2 pB0 = {c2_0[t][2], c2_0[t][3]};
            hilo2(relu2(pA0), ha0[2*t],     la0[2*t]);
            hilo2(relu2(pB0), ha0[2*t + 1], la0[2*t + 1]);
            f32x2 pA0b = {c2_0[t+2][0], c2_0[t+2][1]};
            f32x2 pB0b = {c2_0[t+2][2], c2_0[t+2][3]};
            hilo2(relu2(pA0b), hb0[2*t],     lb0[2*t]);
            hilo2(relu2(pB0b), hb0[2*t + 1], lb0[2*t + 1]);
            f32x2 pA1 = {c2_1[t][0], c2_1[t][1]};
            f32x2 pB1 = {c2_1[t][2], c2_1[t][3]};
            hilo2(relu2(pA1), ha1[2*t],     la1[2*t]);
            hilo2(relu2(pB1), ha1[2*t + 1], la1[2*t + 1]);
            f32x2 pA1b = {c2_1[t+2][0], c2_1[t+2][1]};
            f32x2 pB1b = {c2_1[t+2][2], c2_1[t+2][3]};
            hilo2(relu2(pA1b), hb1[2*t],     lb1[2*t]);
            hilo2(relu2(pB1b), hb1[2*t + 1], lb1[2*t + 1]);
        }
        bf16x8 h30a = frag4(ha0[0], ha0[1], ha0[2], ha0[3]);
        bf16x8 l30a = frag4(la0[0], la0[1], la0[2], la0[3]);
        bf16x8 h30b = frag4(hb0[0], hb0[1], hb0[2], hb0[3]);
        bf16x8 l30b = frag4(lb0[0], lb0[1], lb0[2], lb0[3]);
        bf16x8 h31a = frag4(ha1[0], ha1[1], ha1[2], ha1[3]);
        bf16x8 l31a = frag4(la1[0], la1[1], la1[2], la1[3]);
        bf16x8 h31b = frag4(hb1[0], hb1[1], hb1[2], hb1[3]);
        bf16x8 l31b = frag4(lb1[0], lb1[1], lb1[2], lb1[3]);

        // L3: 4 steps x 2 tiles, W3 frags read once, used by both points
        float s0_0 = 0.f, s1_0 = 0.f, s0_1 = 0.f, s1_1 = 0.f;
        #pragma unroll
        for (int nn = 0; nn < 4; ++nn) {
            bf16x8 c0a = __builtin_bit_cast(bf16x8, w3lds[nn * 4 + 0][lane]);
            bf16x8 c0b = __builtin_bit_cast(bf16x8, w3lds[nn * 4 + 1][lane]);
            bf16x8 c1a = __builtin_bit_cast(bf16x8, w3lds[nn * 4 + 2][lane]);
            bf16x8 c1b = __builtin_bit_cast(bf16x8, w3lds[nn * 4 + 3][lane]);
            f32x4 a00 = {0,0,0,0}, a01 = {0,0,0,0}, a10 = {0,0,0,0}, a11 = {0,0,0,0};
            a00 = MFMA(h30a, c0a, a00); a00 = MFMA(h30b, c0b, a00);
            a00 = MFMA(l30a, c0a, a00); a00 = MFMA(l30b, c0b, a00);
            a01 = MFMA(h30a, c1a, a01); a01 = MFMA(h30b, c1b, a01);
            a01 = MFMA(l30a, c1a, a01); a01 = MFMA(l30b, c1b, a01);
            a10 = MFMA(h31a, c0a, a10); a10 = MFMA(h31b, c0b, a10);
            a10 = MFMA(l31a, c0a, a10); a10 = MFMA(l31b, c0b, a10);
            a11 = MFMA(h31a, c1a, a11); a11 = MFMA(h31b, c1b, a11);
            a11 = MFMA(l31a, c1a, a11); a11 = MFMA(l31b, c1b, a11);
            f32x2 m00 = __builtin_elementwise_max((f32x2){a00[0], a00[1]}, (f32x2){a00[2], a00[3]});
            float v00 = fmaxf(m00[0], m00[1]);
            v00 = fmaxf(v00, __shfl_xor(v00, 16)); v00 = fmaxf(v00, __shfl_xor(v00, 32));
            f32x2 m01 = __builtin_elementwise_max((f32x2){a01[0], a01[1]}, (f32x2){a01[2], a01[3]});
            float v01 = fmaxf(m01[0], m01[1]);
            v01 = fmaxf(v01, __shfl_xor(v01, 16)); v01 = fmaxf(v01, __shfl_xor(v01, 32));
            f32x2 m10 = __builtin_elementwise_max((f32x2){a10[0], a10[1]}, (f32x2){a10[2], a10[3]});
            float v10 = fmaxf(m10[0], m10[1]);
            v10 = fmaxf(v10, __shfl_xor(v10, 16)); v10 = fmaxf(v10, __shfl_xor(v10, 32));
            f32x2 m11 = __builtin_elementwise_max((f32x2){a11[0], a11[1]}, (f32x2){a11[2], a11[3]});
            float v11 = fmaxf(m11[0], m11[1]);
            v11 = fmaxf(v11, __shfl_xor(v11, 16)); v11 = fmaxf(v11, __shfl_xor(v11, 32));
            if (nn == g) { s0_0 = v00; s1_0 = v01; s0_1 = v10; s1_1 = v11; }
        }
        float* o0 = out + ((size_t)(m * 128 + p0) << 7);
        float* o1 = out + ((size_t)(m * 128 + p1) << 7);
        o0[(2 * g) * 16 + ln]     = s0_0 + b3r0;
        o0[(2 * g + 1) * 16 + ln] = s1_0 + b3r1;
        o1[(2 * g) * 16 + ln]     = s0_1 + b3r0;
        o1[(2 * g + 1) * 16 + ln] = s1_1 + b3r1;
    }
}

extern "C" void kernel_launch(void* const* d_in, const int* in_sizes, int n_in,
                              void* d_out, int out_size, void* d_ws, size_t ws_size,
                              hipStream_t stream) {
    const float* windows = (const float*)d_in[0];
    const float* W1 = (const float*)d_in[1];
    const float* b1 = (const float*)d_in[2];
    const float* W2 = (const float*)d_in[3];
    const float* b2 = (const float*)d_in[4];
    const float* W3 = (const float*)d_in[5];
    const float* b3 = (const float*)d_in[6];
    float* out = (float*)d_out;
    hipLaunchKernelGGL(miniemb_kernel, dim3(1024), dim3(256), 0, stream,
                       windows, W1, b1, W2, b2, W3, b3, out);
}

// Round 11
// 215.885 us; speedup vs baseline: 1.2517x; 1.0246x over previous
//
#include <hip/hip_runtime.h>

typedef __bf16 bf16x8 __attribute__((ext_vector_type(8)));
typedef __bf16 bf16x2 __attribute__((ext_vector_type(2)));
typedef float  f32x4  __attribute__((ext_vector_type(4)));
typedef float  f32x2  __attribute__((ext_vector_type(2)));
typedef unsigned long long u64;

#define MFMA(a, b, c) __builtin_amdgcn_mfma_f32_16x16x32_bf16((a), (b), (c), 0, 0, 0)

// Packed fp32 helpers -> v_pk_fma_f32 / v_pk_max_f32 (bit-exact per element).
__device__ __forceinline__ f32x2 fma2(f32x2 a, f32x2 b, f32x2 c) {
    return __builtin_elementwise_fma(a, b, c);
}
__device__ __forceinline__ f32x2 relu2(f32x2 a) {
    f32x2 z = {0.0f, 0.0f};
    return __builtin_elementwise_max(a, z);
}
// Double-bf16 (hi/lo) split of a packed f32 pair; word layout = MFMA frag word.
__device__ __forceinline__ void hilo2(f32x2 h, unsigned& hiw, unsigned& low) {
    bf16x2 hb = __builtin_convertvector(h, bf16x2);
    unsigned hw = __builtin_bit_cast(unsigned, hb);
    f32x2 hf;
    hf[0] = __builtin_bit_cast(float, hw << 16);
    hf[1] = __builtin_bit_cast(float, hw & 0xFFFF0000u);
    f32x2 lo = h - hf;
    bf16x2 lb = __builtin_convertvector(lo, bf16x2);
    hiw = hw;
    low = __builtin_bit_cast(unsigned, lb);
}
__device__ __forceinline__ bf16x8 frag4(unsigned w0, unsigned w1, unsigned w2, unsigned w3) {
    uint4 u; u.x = w0; u.y = w1; u.z = w2; u.w = w3;
    return __builtin_bit_cast(bf16x8, u);
}

// Per-point tail: pack c2 -> L3 frags, run L3 over the shared W3 stream, store.
// MFMA order per accumulator identical to the proven interleaved version
// (hi*a, hi*b, lo*a, lo*b) -> bit-identical output.
__device__ __forceinline__ void tail_point(
    const f32x4 c2[4], const uint4 (*w3)[64],
    int g, int lane, int ln, float b3r0, float b3r1, float* o)
{
    unsigned ha[4], la[4], hb[4], lb[4];
    #pragma unroll
    for (int t = 0; t < 2; ++t) {
        f32x2 pA = {c2[t][0], c2[t][1]};
        f32x2 pB = {c2[t][2], c2[t][3]};
        hilo2(relu2(pA), ha[2*t],     la[2*t]);
        hilo2(relu2(pB), ha[2*t + 1], la[2*t + 1]);
        f32x2 qA = {c2[t+2][0], c2[t+2][1]};
        f32x2 qB = {c2[t+2][2], c2[t+2][3]};
        hilo2(relu2(qA), hb[2*t],     lb[2*t]);
        hilo2(relu2(qB), hb[2*t + 1], lb[2*t + 1]);
    }
    bf16x8 h3a = frag4(ha[0], ha[1], ha[2], ha[3]);
    bf16x8 l3a = frag4(la[0], la[1], la[2], la[3]);
    bf16x8 h3b = frag4(hb[0], hb[1], hb[2], hb[3]);
    bf16x8 l3b = frag4(lb[0], lb[1], lb[2], lb[3]);
    float s0 = 0.f, s1 = 0.f;
    #pragma unroll
    for (int nn = 0; nn < 4; ++nn) {
        bf16x8 c0a = __builtin_bit_cast(bf16x8, w3[nn * 4 + 0][lane]);
        bf16x8 c0b = __builtin_bit_cast(bf16x8, w3[nn * 4 + 1][lane]);
        bf16x8 c1a = __builtin_bit_cast(bf16x8, w3[nn * 4 + 2][lane]);
        bf16x8 c1b = __builtin_bit_cast(bf16x8, w3[nn * 4 + 3][lane]);
        f32x4 a0 = {0,0,0,0}, a1 = {0,0,0,0};
        a0 = MFMA(h3a, c0a, a0); a0 = MFMA(h3b, c0b, a0);
        a0 = MFMA(l3a, c0a, a0); a0 = MFMA(l3b, c0b, a0);
        a1 = MFMA(h3a, c1a, a1); a1 = MFMA(h3b, c1b, a1);
        a1 = MFMA(l3a, c1a, a1); a1 = MFMA(l3b, c1b, a1);
        f32x2 m0 = __builtin_elementwise_max((f32x2){a0[0], a0[1]}, (f32x2){a0[2], a0[3]});
        float v0 = fmaxf(m0[0], m0[1]);
        v0 = fmaxf(v0, __shfl_xor(v0, 16)); v0 = fmaxf(v0, __shfl_xor(v0, 32));
        f32x2 m1 = __builtin_elementwise_max((f32x2){a1[0], a1[1]}, (f32x2){a1[2], a1[3]});
        float v1 = fmaxf(m1[0], m1[1]);
        v1 = fmaxf(v1, __shfl_xor(v1, 16)); v1 = fmaxf(v1, __shfl_xor(v1, 32));
        if (nn == g) { s0 = v0; s1 = v1; }
    }
    o[(2 * g) * 16 + ln]     = s0 + b3r0;
    o[(2 * g + 1) * 16 + ln] = s1 + b3r1;
}

// __launch_bounds__(256, 3): combined budget 170 -> 3 waves/SIMD.
// r9/r10: the spill at this budget is the PHASE-3 PEAK (both points' tails live
// at once), not persistent regs. This version splits the tail per point: while
// point0 runs L2+pack+L3, point1's state doesn't exist -> peak drops ~60 regs.
// Tripwire: FETCH >> 1.3MB -> still spilling -> plain bounds next.
__global__ __launch_bounds__(256, 3) void miniemb_kernel(
    const float* __restrict__ windows,
    const float* __restrict__ W1, const float* __restrict__ b1,
    const float* __restrict__ W2, const float* __restrict__ b2,
    const float* __restrict__ W3, const float* __restrict__ b3,
    float* __restrict__ out)
{
    // LDS total = 24576 + 16384 + 4096 + 256 = 45312 B -> 3 blocks/CU (<=54613).
    __shared__ float relbuf[48 * 128];   // XOR-swizzled: word = t*128 + (p ^ (t&31))
    __shared__ uint4 w3lds[16][64];      // W3 B-frags; first 2 KiB doubles as pts4 in ph1-2
    __shared__ uint4 w2lds[4][64];       // W2 A-frags [t][lane]
    __shared__ float b2lds[64];

    float (*pts4)[4] = reinterpret_cast<float(*)[4]>(&w3lds[0][0]);

    const int m    = blockIdx.x;
    const int tid  = threadIdx.x;
    const int w    = tid >> 6;
    const int lane = tid & 63;
    const int g    = lane >> 4;
    const int ln   = lane & 15;

    // ---- phase 0: stage pts4 (x,y,z,|p|^2) + b2 ----
    const float* wm = windows + (size_t)m * 128 * 3;
    if (tid < 128) {
        float x = wm[tid * 3], y = wm[tid * 3 + 1], z = wm[tid * 3 + 2];
        float s = __fadd_rn(__fadd_rn(__fmul_rn(x, x), __fmul_rn(y, y)),
                            __fmul_rn(z, z));
        f32x4 P = {x, y, z, s};
        *(f32x4*)&pts4[tid][0] = P;
    }
    if (tid < 64) b2lds[tid] = b2[tid];
    __syncthreads();

    // ---- phase 1: kNN scan, 2 threads per point, sorted insert (breadth-wise) ----
    const int k = tid >> 1;      // point
    const int h = tid & 1;       // half
    f32x4 Q = *(const f32x4*)&pts4[k][0];
    u64 bd[16];
    #pragma unroll
    for (int t = 0; t < 16; ++t) bd[t] = ~0ull;
    #pragma unroll 1
    for (int jj = 0; jj < 64; ++jj) {
        const int j = (h << 6) + jj;
        f32x4 P = *(const f32x4*)&pts4[j][0];
        // np-exact d2 (bit-identical to the round-2 proven path)
        float dot = __fadd_rn(__fadd_rn(__fmul_rn(Q.x, P.x),
                                        __fmul_rn(Q.y, P.y)),
                              __fmul_rn(Q.z, P.z));
        float dd = __fsub_rn(__fadd_rn(Q.w, P.w), __fmul_rn(2.0f, dot));
        unsigned u = __float_as_uint(dd);
        unsigned key32 = u ^ (((unsigned)(((int)u) >> 31)) | 0x80000000u);
        u64 kk = ((u64)key32 << 32) | (unsigned)j;
        bool ct[16];
        #pragma unroll
        for (int t = 0; t < 16; ++t) ct[t] = bd[t] < kk;
        #pragma unroll
        for (int t = 15; t >= 1; --t)
            bd[t] = ct[t] ? bd[t] : (ct[t - 1] ? kk : bd[t - 1]);
        bd[0] = ct[0] ? bd[0] : kk;
    }

    // ---- phase 2: lane-pair merge, partner values STREAMED via shuffle ----
    unsigned msk = 0;
    #pragma unroll
    for (int i = 0; i < 16; ++i) {
        u64 o = __shfl_xor(bd[15 - i], 1);   // partner's bd[15-i]
        msk |= (bd[i] < o) ? (1u << i) : 0u;
    }
    const int cnt   = __popc(msk);
    const int rbase = h ? (16 - cnt) : 0;    // A rows: 0..cA-1, B rows: cA..15

    // scale = max norm over selected = sqrt(max d2)  (sqrtf monotone -> bit-identical)
    float m2 = 0.0f;
    #pragma unroll
    for (int i = 0; i < 16; ++i) {
        if (i < cnt) {
            f32x4 P = *(const f32x4*)&pts4[(unsigned)bd[i] & 127u][0];
            float dx = P.x - Q.x, dy = P.y - Q.y, dz = P.z - Q.z;
            m2 = fmaxf(m2, dx * dx + dy * dy + dz * dz);
        }
    }
    m2 = fmaxf(m2, __shfl_xor(m2, 1));
    const float inv = 1.0f / fmaxf(sqrtf(m2), 1e-8f);

    #pragma unroll
    for (int i = 0; i < 16; ++i) {
        if (i < cnt) {
            f32x4 P = *(const f32x4*)&pts4[(unsigned)bd[i] & 127u][0];
            const int t0 = (rbase + i) * 3;
            relbuf[(t0 + 0) * 128 + (k ^ ((t0 + 0) & 31))] = (P.x - Q.x) * inv;
            relbuf[(t0 + 1) * 128 + (k ^ ((t0 + 1) & 31))] = (P.y - Q.y) * inv;
            relbuf[(t0 + 2) * 128 + (k ^ ((t0 + 2) & 31))] = (P.z - Q.z) * inv;
        }
    }
    __syncthreads();   // all pts4 reads done -> safe to overwrite with W3 frags

    // ---- phase 2b: fill w3lds (overwrites pts4 overlay) + w2lds frag table ----
    #pragma unroll
    for (int q = 0; q < 4; ++q) {
        const int f = w * 4 + q, n = f >> 1, kb = f & 1;
        bf16x8 v;
        #pragma unroll
        for (int j = 0; j < 8; ++j)
            v[j] = (__bf16)W3[(kb * 32 + g * 8 + j) * 128 + n * 16 + ln];
        w3lds[f][lane] = __builtin_bit_cast(uint4, v);
    }
    {
        // wave w stages w2lds[w][lane]: frag value depends only on (t=w, lane)
        const int c = 32 * (w >> 1) + 8 * (ln >> 2) + 4 * (w & 1) + (ln & 3);
        bf16x8 v;
        #pragma unroll
        for (int j = 0; j < 8; ++j)
            v[j] = (__bf16)W2[(g * 8 + j) * 64 + c];
        w2lds[w][lane] = __builtin_bit_cast(uint4, v);
    }

    // ---- persistent: only W1/b1 packed pairs + b3 stay in registers ----
    f32x2 w1v0[4], w1v1[4], w1v2[4], b1v[4];
    #pragma unroll
    for (int jj = 0; jj < 4; ++jj) {
        const int c = g * 8 + 2 * jj;
        w1v0[jj] = *(const f32x2*)&W1[c];
        w1v1[jj] = *(const f32x2*)&W1[32 + c];
        w1v2[jj] = *(const f32x2*)&W1[64 + c];
        b1v[jj]  = *(const f32x2*)&b1[c];
    }
    const float b3r0 = b3[(2 * g) * 16 + ln];
    const float b3r1 = b3[(2 * g + 1) * 16 + ln];
    __syncthreads();

    // ---- phase 3: MFMA MLP, 2 points/iter; L1 shared, tail split PER POINT ----
    const float* ra = relbuf + (ln * 3 + 0) * 128;
    const float* rb = relbuf + (ln * 3 + 1) * 128;
    const float* rc = relbuf + (ln * 3 + 2) * 128;
    const int xa = (ln * 3 + 0) & 31;
    const int xb = (ln * 3 + 1) & 31;
    const int xc = (ln * 3 + 2) & 31;

    #pragma unroll 1
    for (int i = 0; i < 16; ++i) {
        const int p0 = w * 32 + 2 * i;
        const int p1 = p0 + 1;
        const float r00 = ra[p0 ^ xa], r01 = rb[p0 ^ xb], r02 = rc[p0 ^ xc];
        const float r10 = ra[p1 ^ xa], r11 = rb[p1 ^ xb], r12 = rc[p1 ^ xc];
        const f32x2 r00v = {r00, r00}, r01v = {r01, r01}, r02v = {r02, r02};
        const f32x2 r10v = {r10, r10}, r11v = {r11, r11}, r12v = {r12, r12};

        // L1 both points: packed over column pairs; cvt_pk words ARE the frags
        unsigned h0w[4], l0w[4], h1w[4], l1w[4];
        #pragma unroll
        for (int jj = 0; jj < 4; ++jj) {
            f32x2 hv0 = fma2(r02v, w1v2[jj], fma2(r01v, w1v1[jj], fma2(r00v, w1v0[jj], b1v[jj])));
            hilo2(relu2(hv0), h0w[jj], l0w[jj]);
            f32x2 hv1 = fma2(r12v, w1v2[jj], fma2(r11v, w1v1[jj], fma2(r10v, w1v0[jj], b1v[jj])));
            hilo2(relu2(hv1), h1w[jj], l1w[jj]);
        }
        bf16x8 a1hi0 = frag4(h0w[0], h0w[1], h0w[2], h0w[3]);
        bf16x8 a1lo0 = frag4(l0w[0], l0w[1], l0w[2], l0w[3]);
        bf16x8 a1hi1 = frag4(h1w[0], h1w[1], h1w[2], h1w[3]);
        bf16x8 a1lo1 = frag4(l1w[0], l1w[1], l1w[2], l1w[3]);

        // ---- point 0: L2 + pack + L3 + store (point 1 state not yet live) ----
        {
            f32x4 c2[4];
            #pragma unroll
            for (int t = 0; t < 4; ++t) {
                bf16x8 w2f = __builtin_bit_cast(bf16x8, w2lds[t][lane]);
                f32x4 acc = *(const f32x4*)&b2lds[32 * (t >> 1) + 8 * g + 4 * (t & 1)];
                acc = MFMA(w2f, a1hi0, acc);
                acc = MFMA(w2f, a1lo0, acc);
                c2[t] = acc;
            }
            tail_point(c2, w3lds, g, lane, ln, b3r0, b3r1,
                       out + ((size_t)(m * 128 + p0) << 7));
        }
        // ---- point 1 ----
        {
            f32x4 c2[4];
            #pragma unroll
            for (int t = 0; t < 4; ++t) {
                bf16x8 w2f = __builtin_bit_cast(bf16x8, w2lds[t][lane]);
                f32x4 acc = *(const f32x4*)&b2lds[32 * (t >> 1) + 8 * g + 4 * (t & 1)];
                acc = MFMA(w2f, a1hi1, acc);
                acc = MFMA(w2f, a1lo1, acc);
                c2[t] = acc;
            }
            tail_point(c2, w3lds, g, lane, ln, b3r0, b3r1,
                       out + ((size_t)(m * 128 + p1) << 7));
        }
    }
}

extern "C" void kernel_launch(void* const* d_in, const int* in_sizes, int n_in,
                              void* d_out, int out_size, void* d_ws, size_t ws_size,
                              hipStream_t stream) {
    const float* windows = (const float*)d_in[0];
    const float* W1 = (const float*)d_in[1];
    const float* b1 = (const float*)d_in[2];
    const float* W2 = (const float*)d_in[3];
    const float* b2 = (const float*)d_in[4];
    const float* W3 = (const float*)d_in[5];
    const float* b3 = (const float*)d_in[6];
    float* out = (float*)d_out;
    hipLaunchKernelGGL(miniemb_kernel, dim3(1024), dim3(256), 0, stream,
                       windows, W1, b1, W2, b2, W3, b3, out);
}

// Round 13
// 202.333 us; speedup vs baseline: 1.3356x; 1.0670x over previous
//
#include <hip/hip_runtime.h>

typedef __bf16 bf16x8 __attribute__((ext_vector_type(8)));
typedef __bf16 bf16x2 __attribute__((ext_vector_type(2)));
typedef float  f32x4  __attribute__((ext_vector_type(4)));
typedef float  f32x2  __attribute__((ext_vector_type(2)));

#define MFMA(a, b, c) __builtin_amdgcn_mfma_f32_16x16x32_bf16((a), (b), (c), 0, 0, 0)

// Packed fp32 helpers -> v_pk_fma_f32 / v_pk_max_f32 (bit-exact per element).
__device__ __forceinline__ f32x2 fma2(f32x2 a, f32x2 b, f32x2 c) {
    return __builtin_elementwise_fma(a, b, c);
}
__device__ __forceinline__ f32x2 relu2(f32x2 a) {
    f32x2 z = {0.0f, 0.0f};
    return __builtin_elementwise_max(a, z);
}
// Double-bf16 (hi/lo) split of a packed f32 pair; word layout = MFMA frag word.
__device__ __forceinline__ void hilo2(f32x2 h, unsigned& hiw, unsigned& low) {
    bf16x2 hb = __builtin_convertvector(h, bf16x2);
    unsigned hw = __builtin_bit_cast(unsigned, hb);
    f32x2 hf;
    hf[0] = __builtin_bit_cast(float, hw << 16);
    hf[1] = __builtin_bit_cast(float, hw & 0xFFFF0000u);
    f32x2 lo = h - hf;
    bf16x2 lb = __builtin_convertvector(lo, bf16x2);
    hiw = hw;
    low = __builtin_bit_cast(unsigned, lb);
}
__device__ __forceinline__ bf16x8 frag4(unsigned w0, unsigned w1, unsigned w2, unsigned w3) {
    uint4 u; u.x = w0; u.y = w1; u.z = w2; u.w = w3;
    return __builtin_bit_cast(bf16x8, u);
}
// Key = key32*128 + j as an f64: integer-exact (39 bits < 52), nonnegative ->
// f64 ordering == (key32, j) lex order == the proven u64 key order.
__device__ __forceinline__ unsigned key_idx(double key) {
    double q = trunc(key * 0.0078125);           // key/128, pow2 scale: exact
    return (unsigned)(key - q * 128.0);          // exact integer 0..127
}

// Plain __launch_bounds__(256): rounds 8-11 proved the occupancy line is dead
// (issue-bound: VALUBusy 74% + MfmaUtil 23% ~ 97% of slots; every forced-budget
// variant spilled and lost). This is the round-7 158us kernel with ONE change:
// phase-1 keys u64 -> f64, so the sorted-insert becomes
//   new_bd[t] = min_f64(max_f64(bd[t-1], kk), bd[t])
// (~31 ops/candidate vs ~80 for cmp_u64 + u64 cndmask chains). Selection is
// bit-identical: same lex order, no ties (index embedded).
__global__ __launch_bounds__(256) void miniemb_kernel(
    const float* __restrict__ windows,
    const float* __restrict__ W1, const float* __restrict__ b1,
    const float* __restrict__ W2, const float* __restrict__ b2,
    const float* __restrict__ W3, const float* __restrict__ b3,
    float* __restrict__ out)
{
    // LDS total = 24576 + 16384 = 40960 B.
    __shared__ float relbuf[48 * 128];   // XOR-swizzled: word = t*128 + (p ^ (t&31))
    __shared__ uint4 w3lds[16][64];      // W3 B-frags; first 2 KiB doubles as pts4 in ph1-2

    float (*pts4)[4] = reinterpret_cast<float(*)[4]>(&w3lds[0][0]);

    const int m    = blockIdx.x;
    const int tid  = threadIdx.x;
    const int w    = tid >> 6;
    const int lane = tid & 63;
    const int g    = lane >> 4;
    const int ln   = lane & 15;

    // ---- phase 0: stage pts4 (x,y,z,|p|^2) -- W3 fill deferred to after phase 2 ----
    const float* wm = windows + (size_t)m * 128 * 3;
    if (tid < 128) {
        float x = wm[tid * 3], y = wm[tid * 3 + 1], z = wm[tid * 3 + 2];
        float s = __fadd_rn(__fadd_rn(__fmul_rn(x, x), __fmul_rn(y, y)),
                            __fmul_rn(z, z));
        f32x4 P = {x, y, z, s};
        *(f32x4*)&pts4[tid][0] = P;
    }
    __syncthreads();

    // ---- phase 1: kNN scan, 2 threads per point, f64 min/max sorted insert ----
    const int k = tid >> 1;      // point
    const int h = tid & 1;       // half
    f32x4 Q = *(const f32x4*)&pts4[k][0];
    double bd[16];
    #pragma unroll
    for (int t = 0; t < 16; ++t) bd[t] = 1e300;   // > any real key
    #pragma unroll 1
    for (int jj = 0; jj < 64; ++jj) {
        const int j = (h << 6) + jj;
        f32x4 P = *(const f32x4*)&pts4[j][0];
        // np-exact d2 (bit-identical to the round-2 proven path)
        float dot = __fadd_rn(__fadd_rn(__fmul_rn(Q.x, P.x),
                                        __fmul_rn(Q.y, P.y)),
                              __fmul_rn(Q.z, P.z));
        float dd = __fsub_rn(__fadd_rn(Q.w, P.w), __fmul_rn(2.0f, dot));
        unsigned u = __float_as_uint(dd);
        unsigned key32 = u ^ (((unsigned)(((int)u) >> 31)) | 0x80000000u);
        double kk = (double)key32 * 128.0 + (double)j;   // exact 39-bit integer
        // sorted-insert, drop max: new[t] = min(max(old[t-1], kk), old[t]).
        // Descending t reads only OLD values (breadth form, 2-deep dep chain).
        #pragma unroll
        for (int t = 15; t >= 1; --t)
            bd[t] = fmin(fmax(bd[t - 1], kk), bd[t]);
        bd[0] = fmin(bd[0], kk);
    }

    // ---- phase 2: lane-pair merge, partner values STREAMED via shuffle ----
    // Keys embed the index -> no ties -> strict < exact for BOTH lanes.
    unsigned msk = 0;
    #pragma unroll
    for (int i = 0; i < 16; ++i) {
        double o = __shfl_xor(bd[15 - i], 1);   // partner's bd[15-i]
        msk |= (bd[i] < o) ? (1u << i) : 0u;
    }
    const int cnt   = __popc(msk);
    const int rbase = h ? (16 - cnt) : 0;    // A rows: 0..cA-1, B rows: cA..15

    // scale = max norm over selected = sqrt(max d2)  (sqrtf monotone -> bit-identical)
    float m2 = 0.0f;
    #pragma unroll
    for (int i = 0; i < 16; ++i) {
        if (i < cnt) {
            f32x4 P = *(const f32x4*)&pts4[key_idx(bd[i])][0];
            float dx = P.x - Q.x, dy = P.y - Q.y, dz = P.z - Q.z;
            m2 = fmaxf(m2, dx * dx + dy * dy + dz * dz);
        }
    }
    m2 = fmaxf(m2, __shfl_xor(m2, 1));
    const float inv = 1.0f / fmaxf(sqrtf(m2), 1e-8f);

    #pragma unroll
    for (int i = 0; i < 16; ++i) {
        if (i < cnt) {
            f32x4 P = *(const f32x4*)&pts4[key_idx(bd[i])][0];
            const int t0 = (rbase + i) * 3;
            relbuf[(t0 + 0) * 128 + (k ^ ((t0 + 0) & 31))] = (P.x - Q.x) * inv;
            relbuf[(t0 + 1) * 128 + (k ^ ((t0 + 1) & 31))] = (P.y - Q.y) * inv;
            relbuf[(t0 + 2) * 128 + (k ^ ((t0 + 2) & 31))] = (P.z - Q.z) * inv;
        }
    }
    __syncthreads();   // all pts4 reads done -> safe to overwrite with W3 frags

    // ---- phase 2b: fill w3lds (overwrites the pts4 overlay region) ----
    #pragma unroll
    for (int q = 0; q < 4; ++q) {
        const int f = w * 4 + q, n = f >> 1, kb = f & 1;
        bf16x8 v;
        #pragma unroll
        for (int j = 0; j < 8; ++j)
            v[j] = (__bf16)W3[(kb * 32 + g * 8 + j) * 128 + n * 16 + ln];
        w3lds[f][lane] = __builtin_bit_cast(uint4, v);
    }

    // ---- persistent weight fragments (after kNN: caps register pressure) ----
    bf16x8 w2A[4];
    #pragma unroll
    for (int t = 0; t < 4; ++t) {
        const int c = 32 * (t >> 1) + 8 * (ln >> 2) + 4 * (t & 1) + (ln & 3);
        #pragma unroll
        for (int j = 0; j < 8; ++j)
            w2A[t][j] = (__bf16)W2[(g * 8 + j) * 64 + c];
    }
    float b2p[16];
    #pragma unroll
    for (int t = 0; t < 4; ++t)
        #pragma unroll
        for (int r = 0; r < 4; ++r)
            b2p[t * 4 + r] = b2[32 * (t >> 1) + 8 * g + 4 * (t & 1) + r];
    // W1/b1 as packed f32x2 over column pairs (c = g*8 + 2*jj + e)
    f32x2 w1v0[4], w1v1[4], w1v2[4], b1v[4];
    #pragma unroll
    for (int jj = 0; jj < 4; ++jj) {
        const int c = g * 8 + 2 * jj;
        w1v0[jj] = *(const f32x2*)&W1[c];
        w1v1[jj] = *(const f32x2*)&W1[32 + c];
        w1v2[jj] = *(const f32x2*)&W1[64 + c];
        b1v[jj]  = *(const f32x2*)&b1[c];
    }
    const float b3r0 = b3[(2 * g) * 16 + ln];
    const float b3r1 = b3[(2 * g + 1) * 16 + ln];
    __syncthreads();

    // ---- phase 3: MFMA MLP, 2 points per iteration, packed-fp32 VALU ----
    const float* ra = relbuf + (ln * 3 + 0) * 128;
    const float* rb = relbuf + (ln * 3 + 1) * 128;
    const float* rc = relbuf + (ln * 3 + 2) * 128;
    const int xa = (ln * 3 + 0) & 31;
    const int xb = (ln * 3 + 1) & 31;
    const int xc = (ln * 3 + 2) & 31;

    #pragma unroll 1
    for (int i = 0; i < 16; ++i) {
        const int p0 = w * 32 + 2 * i;
        const int p1 = p0 + 1;
        const float r00 = ra[p0 ^ xa], r01 = rb[p0 ^ xb], r02 = rc[p0 ^ xc];
        const float r10 = ra[p1 ^ xa], r11 = rb[p1 ^ xb], r12 = rc[p1 ^ xc];
        const f32x2 r00v = {r00, r00}, r01v = {r01, r01}, r02v = {r02, r02};
        const f32x2 r10v = {r10, r10}, r11v = {r11, r11}, r12v = {r12, r12};

        // L1 both points: packed over column pairs; cvt_pk words ARE the frags
        unsigned h0w[4], l0w[4], h1w[4], l1w[4];
        #pragma unroll
        for (int jj = 0; jj < 4; ++jj) {
            f32x2 hv0 = fma2(r02v, w1v2[jj], fma2(r01v, w1v1[jj], fma2(r00v, w1v0[jj], b1v[jj])));
            hilo2(relu2(hv0), h0w[jj], l0w[jj]);
            f32x2 hv1 = fma2(r12v, w1v2[jj], fma2(r11v, w1v1[jj], fma2(r10v, w1v0[jj], b1v[jj])));
            hilo2(relu2(hv1), h1w[jj], l1w[jj]);
        }
        bf16x8 a1hi0 = frag4(h0w[0], h0w[1], h0w[2], h0w[3]);
        bf16x8 a1lo0 = frag4(l0w[0], l0w[1], l0w[2], l0w[3]);
        bf16x8 a1hi1 = frag4(h1w[0], h1w[1], h1w[2], h1w[3]);
        bf16x8 a1lo1 = frag4(l1w[0], l1w[1], l1w[2], l1w[3]);

        // L2 transposed, both points
        f32x4 c2_0[4], c2_1[4];
        #pragma unroll
        for (int t = 0; t < 4; ++t) {
            f32x4 acc0 = {b2p[t*4+0], b2p[t*4+1], b2p[t*4+2], b2p[t*4+3]};
            f32x4 acc1 = acc0;
            acc0 = MFMA(w2A[t], a1hi0, acc0);
            acc1 = MFMA(w2A[t], a1hi1, acc1);
            acc0 = MFMA(w2A[t], a1lo0, acc0);
            acc1 = MFMA(w2A[t], a1lo1, acc1);
            c2_0[t] = acc0; c2_1[t] = acc1;
        }

        // relu + hi/lo pack into L3 A-frags (packed pairs; word jj = elems 2jj,2jj+1)
        unsigned ha0[4], la0[4], hb0[4], lb0[4];   // point0: t<2 -> "a", t>=2 -> "b"
        unsigned ha1[4], la1[4], hb1[4], lb1[4];   // point1
        #pragma unroll
        for (int t = 0; t < 2; ++t) {
            f32x2 pA0 = {c2_0[t][0], c2_0[t][1]};
            f32x2 pB0 = {c2_0[t][2], c2_0[t][3]};
            hilo2(relu2(pA0), ha0[2*t],     la0[2*t]);
            hilo2(relu2(pB0), ha0[2*t + 1], la0[2*t + 1]);
            f32x2 pA0b = {c2_0[t+2][0], c2_0[t+2][1]};
            f32x2 pB0b = {c2_0[t+2][2], c2_0[t+2][3]};
            hilo2(relu2(pA0b), hb0[2*t],     lb0[2*t]);
            hilo2(relu2(pB0b), hb0[2*t + 1], lb0[2*t + 1]);
            f32x2 pA1 = {c2_1[t][0], c2_1[t][1]};
            f32x2 pB1 = {c2_1[t][2], c2_1[t][3]};
            hilo2(relu2(pA1), ha1[2*t],     la1[2*t]);
            hilo2(relu2(pB1), ha1[2*t + 1], la1[2*t + 1]);
            f32x2 pA1b = {c2_1[t+2][0], c2_1[t+2][1]};
            f32x2 pB1b = {c2_1[t+2][2], c2_1[t+2][3]};
            hilo2(relu2(pA1b), hb1[2*t],     lb1[2*t]);
            hilo2(relu2(pB1b), hb1[2*t + 1], lb1[2*t + 1]);
        }
        bf16x8 h30a = frag4(ha0[0], ha0[1], ha0[2], ha0[3]);
        bf16x8 l30a = frag4(la0[0], la0[1], la0[2], la0[3]);
        bf16x8 h30b = frag4(hb0[0], hb0[1], hb0[2], hb0[3]);
        bf16x8 l30b = frag4(lb0[0], lb0[1], lb0[2], lb0[3]);
        bf16x8 h31a = frag4(ha1[0], ha1[1], ha1[2], ha1[3]);
        bf16x8 l31a = frag4(la1[0], la1[1], la1[2], la1[3]);
        bf16x8 h31b = frag4(hb1[0], hb1[1], hb1[2], hb1[3]);
        bf16x8 l31b = frag4(lb1[0], lb1[1], lb1[2], lb1[3]);

        // L3: 4 steps x 2 tiles, W3 frags read once, used by both points
        float s0_0 = 0.f, s1_0 = 0.f, s0_1 = 0.f, s1_1 = 0.f;
        #pragma unroll
        for (int nn = 0; nn < 4; ++nn) {
            bf16x8 c0a = __builtin_bit_cast(bf16x8, w3lds[nn * 4 + 0][lane]);
            bf16x8 c0b = __builtin_bit_cast(bf16x8, w3lds[nn * 4 + 1][lane]);
            bf16x8 c1a = __builtin_bit_cast(bf16x8, w3lds[nn * 4 + 2][lane]);
            bf16x8 c1b = __builtin_bit_cast(bf16x8, w3lds[nn * 4 + 3][lane]);
            f32x4 a00 = {0,0,0,0}, a01 = {0,0,0,0}, a10 = {0,0,0,0}, a11 = {0,0,0,0};
            a00 = MFMA(h30a, c0a, a00); a00 = MFMA(h30b, c0b, a00);
            a00 = MFMA(l30a, c0a, a00); a00 = MFMA(l30b, c0b, a00);
            a01 = MFMA(h30a, c1a, a01); a01 = MFMA(h30b, c1b, a01);
            a01 = MFMA(l30a, c1a, a01); a01 = MFMA(l30b, c1b, a01);
            a10 = MFMA(h31a, c0a, a10); a10 = MFMA(h31b, c0b, a10);
            a10 = MFMA(l31a, c0a, a10); a10 = MFMA(l31b, c0b, a10);
            a11 = MFMA(h31a, c1a, a11); a11 = MFMA(h31b, c1b, a11);
            a11 = MFMA(l31a, c1a, a11); a11 = MFMA(l31b, c1b, a11);
            f32x2 m00 = __builtin_elementwise_max((f32x2){a00[0], a00[1]}, (f32x2){a00[2], a00[3]});
            float v00 = fmaxf(m00[0], m00[1]);
            v00 = fmaxf(v00, __shfl_xor(v00, 16)); v00 = fmaxf(v00, __shfl_xor(v00, 32));
            f32x2 m01 = __builtin_elementwise_max((f32x2){a01[0], a01[1]}, (f32x2){a01[2], a01[3]});
            float v01 = fmaxf(m01[0], m01[1]);
            v01 = fmaxf(v01, __shfl_xor(v01, 16)); v01 = fmaxf(v01, __shfl_xor(v01, 32));
            f32x2 m10 = __builtin_elementwise_max((f32x2){a10[0], a10[1]}, (f32x2){a10[2], a10[3]});
            float v10 = fmaxf(m10[0], m10[1]);
            v10 = fmaxf(v10, __shfl_xor(v10, 16)); v10 = fmaxf(v10, __shfl_xor(v10, 32));
            f32x2 m11 = __builtin_elementwise_max((f32x2){a11[0], a11[1]}, (f32x2){a11[2], a11[3]});
            float v11 = fmaxf(m11[0], m11[1]);
            v11 = fmaxf(v11, __shfl_xor(v11, 16)); v11 = fmaxf(v11, __shfl_xor(v11, 32));
            if (nn == g) { s0_0 = v00; s1_0 = v01; s0_1 = v10; s1_1 = v11; }
        }
        float* o0 = out + ((size_t)(m * 128 + p0) << 7);
        float* o1 = out + ((size_t)(m * 128 + p1) << 7);
        o0[(2 * g) * 16 + ln]     = s0_0 + b3r0;
        o0[(2 * g + 1) * 16 + ln] = s1_0 + b3r1;
        o1[(2 * g) * 16 + ln]     = s0_1 + b3r0;
        o1[(2 * g + 1) * 16 + ln] = s1_1 + b3r1;
    }
}

extern "C" void kernel_launch(void* const* d_in, const int* in_sizes, int n_in,
                              void* d_out, int out_size, void* d_ws, size_t ws_size,
                              hipStream_t stream) {
    const float* windows = (const float*)d_in[0];
    const float* W1 = (const float*)d_in[1];
    const float* b1 = (const float*)d_in[2];
    const float* W2 = (const float*)d_in[3];
    const float* b2 = (const float*)d_in[4];
    const float* W3 = (const float*)d_in[5];
    const float* b3 = (const float*)d_in[6];
    float* out = (float*)d_out;
    hipLaunchKernelGGL(miniemb_kernel, dim3(1024), dim3(256), 0, stream,
                       windows, W1, b1, W2, b2, W3, b3, out);
}